// Round 1
// baseline (1995.421 us; speedup 1.0000x reference)
//
#include <hip/hip_runtime.h>
#include <cstddef>

#define NB 2
#define NH 16
#define SQ 2048
#define DM 1024
#define DH 64
#define WN 128

// ---------------------------------------------------------------------------
// fp32 tiled GEMM: C = A @ W^T + bias      A:[M,K] row-major, W:[N,K] row-major
// MODE 0: O[m*N + n]          (plain row-major, used for out-projection)
// MODE 1: O[((b*NH + n/64)*SQ + s)*64 + (n%64)]   (QKV -> [B,H,S,dh] layout)
// blockIdx.z selects {W0,b0,O0} / {W1,b1,O1} / {W2,b2,O2}
// ---------------------------------------------------------------------------
template <int MODE>
__global__ __launch_bounds__(256) void gemm_xwt(
    const float* __restrict__ A,
    const float* __restrict__ W0, const float* __restrict__ W1,
    const float* __restrict__ W2,
    const float* __restrict__ b0, const float* __restrict__ b1,
    const float* __restrict__ b2,
    float* __restrict__ O0, float* __restrict__ O1, float* __restrict__ O2)
{
    constexpr int TM = 128, TN = 128, BK = 32, K = DM, N = DM;

    const float* W  = (blockIdx.z == 0) ? W0 : (blockIdx.z == 1) ? W1 : W2;
    const float* bb = (blockIdx.z == 0) ? b0 : (blockIdx.z == 1) ? b1 : b2;
    float*       O  = (blockIdx.z == 0) ? O0 : (blockIdx.z == 1) ? O1 : O2;

    __shared__ float As[BK][TM + 4];
    __shared__ float Bs[BK][TN + 4];

    const int t  = threadIdx.x;
    const int m0 = blockIdx.y * TM;
    const int n0 = blockIdx.x * TN;

    // global->LDS load mapping: 4 passes, each wave covers 8 rows x 128B
    const int lrow = t >> 3;        // 0..31 (+32 per pass)
    const int lk   = (t & 7) * 4;   // k offset within tile: 0,4,...,28

    // compute mapping: 8x8 microtile
    const int tx = t & 15;          // n group
    const int ty = t >> 4;          // m group

    float acc[8][8];
#pragma unroll
    for (int i = 0; i < 8; ++i)
#pragma unroll
        for (int j = 0; j < 8; ++j) acc[i][j] = 0.f;

    for (int k0 = 0; k0 < K; k0 += BK) {
        float4 av[4], wv[4];
#pragma unroll
        for (int p = 0; p < 4; ++p) {
            const int r = lrow + p * 32;
            av[p] = *(const float4*)(A + (size_t)(m0 + r) * K + k0 + lk);
            wv[p] = *(const float4*)(W + (size_t)(n0 + r) * K + k0 + lk);
        }
        __syncthreads();   // previous iter's LDS reads must finish
#pragma unroll
        for (int p = 0; p < 4; ++p) {
            const int r = lrow + p * 32;
            As[lk + 0][r] = av[p].x; As[lk + 1][r] = av[p].y;
            As[lk + 2][r] = av[p].z; As[lk + 3][r] = av[p].w;
            Bs[lk + 0][r] = wv[p].x; Bs[lk + 1][r] = wv[p].y;
            Bs[lk + 2][r] = wv[p].z; Bs[lk + 3][r] = wv[p].w;
        }
        __syncthreads();
#pragma unroll
        for (int k = 0; k < BK; ++k) {
            const float4 a0 = *(const float4*)&As[k][ty * 8];
            const float4 a1 = *(const float4*)&As[k][ty * 8 + 4];
            const float4 w0 = *(const float4*)&Bs[k][tx * 8];
            const float4 w1 = *(const float4*)&Bs[k][tx * 8 + 4];
            const float am[8] = {a0.x, a0.y, a0.z, a0.w, a1.x, a1.y, a1.z, a1.w};
            const float bn[8] = {w0.x, w0.y, w0.z, w0.w, w1.x, w1.y, w1.z, w1.w};
#pragma unroll
            for (int i = 0; i < 8; ++i)
#pragma unroll
                for (int j = 0; j < 8; ++j)
                    acc[i][j] = fmaf(am[i], bn[j], acc[i][j]);
        }
    }

    const int n = n0 + tx * 8;
    const float4 bv0 = *(const float4*)(bb + n);
    const float4 bv1 = *(const float4*)(bb + n + 4);

    if (MODE == 0) {
#pragma unroll
        for (int r = 0; r < 8; ++r) {
            const int m = m0 + ty * 8 + r;
            float4 o0 = {acc[r][0] + bv0.x, acc[r][1] + bv0.y,
                         acc[r][2] + bv0.z, acc[r][3] + bv0.w};
            float4 o1 = {acc[r][4] + bv1.x, acc[r][5] + bv1.y,
                         acc[r][6] + bv1.z, acc[r][7] + bv1.w};
            *(float4*)(O + (size_t)m * N + n)     = o0;
            *(float4*)(O + (size_t)m * N + n + 4) = o1;
        }
    } else {
        const int h = n >> 6, d = n & 63;   // 8 contiguous d's stay in one head
#pragma unroll
        for (int r = 0; r < 8; ++r) {
            const int m = m0 + ty * 8 + r;
            const int b = m >> 11, s = m & (SQ - 1);
            const size_t off = ((size_t)(b * NH + h) * SQ + s) * DH + d;
            float4 o0 = {acc[r][0] + bv0.x, acc[r][1] + bv0.y,
                         acc[r][2] + bv0.z, acc[r][3] + bv0.w};
            float4 o1 = {acc[r][4] + bv1.x, acc[r][5] + bv1.y,
                         acc[r][6] + bv1.z, acc[r][7] + bv1.w};
            *(float4*)(O + off)     = o0;
            *(float4*)(O + off + 4) = o1;
        }
    }
}

// ---------------------------------------------------------------------------
// Sliding-window attention: one 64-lane wave per (b, h, query i).
// Lane = dh index for dots/ctx; scores distributed 5 slots/lane.
// Writes the FULL attn row (zeros outside band) -> no separate memset pass.
// ---------------------------------------------------------------------------
__global__ __launch_bounds__(64) void attn_win(
    const float* __restrict__ Q, const float* __restrict__ K,
    const float* __restrict__ V, float* __restrict__ attn,
    float* __restrict__ ctx)
{
    const int lane = threadIdx.x;
    const int i = blockIdx.x, h = blockIdx.y, b = blockIdx.z;
    const int bh = b * NH + h;

    const int j0 = max(i - WN, 0);
    const int j1 = min(i + WN, SQ - 1);
    const int nj = j1 - j0 + 1;          // 129..257

    const float* Kb = K + ((size_t)bh * SQ + j0) * DH;
    const float* Vb = V + ((size_t)bh * SQ + j0) * DH;
    const float  qv = Q[((size_t)bh * SQ + i) * DH + lane];

    float sc[5];
#pragma unroll
    for (int sl = 0; sl < 5; ++sl) sc[sl] = -1e30f;

#pragma unroll
    for (int sl = 0; sl < 5; ++sl) {
        const int base = sl * 64;
        if (base < nj) {
            const int lim = min(64, nj - base);
            for (int u = 0; u < lim; ++u) {
                float s = qv * Kb[(size_t)(base + u) * DH + lane];
                s += __shfl_xor(s, 32); s += __shfl_xor(s, 16);
                s += __shfl_xor(s, 8);  s += __shfl_xor(s, 4);
                s += __shfl_xor(s, 2);  s += __shfl_xor(s, 1);
                if (lane == u) sc[sl] = s * 0.125f;   // 1/sqrt(64)
            }
        }
    }

    // softmax over distributed scores (invalid entries = -1e30 -> exp = 0)
    float mx = sc[0];
#pragma unroll
    for (int sl = 1; sl < 5; ++sl) mx = fmaxf(mx, sc[sl]);
    mx = fmaxf(mx, __shfl_xor(mx, 32)); mx = fmaxf(mx, __shfl_xor(mx, 16));
    mx = fmaxf(mx, __shfl_xor(mx, 8));  mx = fmaxf(mx, __shfl_xor(mx, 4));
    mx = fmaxf(mx, __shfl_xor(mx, 2));  mx = fmaxf(mx, __shfl_xor(mx, 1));

    float e[5], lsum = 0.f;
#pragma unroll
    for (int sl = 0; sl < 5; ++sl) { e[sl] = __expf(sc[sl] - mx); lsum += e[sl]; }
    lsum += __shfl_xor(lsum, 32); lsum += __shfl_xor(lsum, 16);
    lsum += __shfl_xor(lsum, 8);  lsum += __shfl_xor(lsum, 4);
    lsum += __shfl_xor(lsum, 2);  lsum += __shfl_xor(lsum, 1);
    const float inv = 1.0f / lsum;

    __shared__ float pls[320];
#pragma unroll
    for (int sl = 0; sl < 5; ++sl) pls[sl * 64 + lane] = e[sl] * inv;
    __syncthreads();

    // full attn row: band probabilities + explicit zeros elsewhere
    float* arow = attn + ((size_t)bh * SQ + i) * SQ;
#pragma unroll 4
    for (int s32 = 0; s32 < SQ / 64; ++s32) {
        const int j  = s32 * 64 + lane;
        const int jj = j - j0;
        const int jc = jj < 0 ? 0 : (jj > 319 ? 319 : jj);   // clamp LDS index
        const float pv = ((unsigned)jj < (unsigned)nj) ? pls[jc] : 0.f;
        arow[j] = pv;
    }

    // ctx = P @ V  (p broadcast from LDS, lane = dh index)
    float acc = 0.f;
#pragma unroll
    for (int sl = 0; sl < 5; ++sl) {
        const int base = sl * 64;
        if (base < nj) {
            const int lim = min(64, nj - base);
            for (int u = 0; u < lim; ++u)
                acc = fmaf(pls[base + u], Vb[(size_t)(base + u) * DH + lane], acc);
        }
    }
    // ctx layout [B,S,D] so the out-projection is a plain GEMM
    ctx[((size_t)(b * SQ + i)) * DM + h * DH + lane] = acc;
}

// ---------------------------------------------------------------------------
extern "C" void kernel_launch(void* const* d_in, const int* in_sizes, int n_in,
                              void* d_out, int out_size, void* d_ws, size_t ws_size,
                              hipStream_t stream)
{
    const float* x  = (const float*)d_in[0];
    const float* Wq = (const float*)d_in[1];
    const float* bq = (const float*)d_in[2];
    const float* Wk = (const float*)d_in[3];
    const float* bk = (const float*)d_in[4];
    const float* Wv = (const float*)d_in[5];
    const float* bv = (const float*)d_in[6];
    const float* Wo = (const float*)d_in[7];
    const float* bo = (const float*)d_in[8];

    float* out  = (float*)d_out;
    float* attn = out + (size_t)NB * SQ * DM;           // outputs concatenated

    const size_t qkv = (size_t)NB * NH * SQ * DH;       // 4,194,304 floats
    float* Qw = (float*)d_ws;
    float* Kw = Qw + qkv;
    float* Vw = Kw + qkv;
    float* Cw = Vw + qkv;                               // total ws: 67 MB

    // 1) QKV projections (fused via grid.z)
    gemm_xwt<1><<<dim3(DM / 128, (NB * SQ) / 128, 3), dim3(256), 0, stream>>>(
        x, Wq, Wk, Wv, bq, bk, bv, Qw, Kw, Vw);

    // 2) banded attention + full attn-row write + ctx
    attn_win<<<dim3(SQ, NH, NB), dim3(64), 0, stream>>>(Qw, Kw, Vw, attn, Cw);

    // 3) output projection
    gemm_xwt<0><<<dim3(DM / 128, (NB * SQ) / 128, 1), dim3(256), 0, stream>>>(
        Cw, Wo, Wo, Wo, bo, bo, bo, out, out, out);
}

// Round 2
// 1590.854 us; speedup vs baseline: 1.2543x; 1.2543x over previous
//
#include <hip/hip_runtime.h>
#include <cstddef>

#define NB 2
#define NH 16
#define SQ 2048
#define DM 1024
#define DH 64
#define WN 128

// ---------------------------------------------------------------------------
// fp32 tiled GEMM: C = A @ W^T + bias      A:[M,K] row-major, W:[N,K] row-major
// MODE 0: O[m*N + n]          (plain row-major, used for out-projection)
// MODE 1: O[((b*NH + n/64)*SQ + s)*64 + (n%64)]   (QKV -> [B,H,S,dh] layout)
// blockIdx.z selects {W0,b0,O0} / {W1,b1,O1} / {W2,b2,O2}
// ---------------------------------------------------------------------------
template <int MODE>
__global__ __launch_bounds__(256) void gemm_xwt(
    const float* __restrict__ A,
    const float* __restrict__ W0, const float* __restrict__ W1,
    const float* __restrict__ W2,
    const float* __restrict__ b0, const float* __restrict__ b1,
    const float* __restrict__ b2,
    float* __restrict__ O0, float* __restrict__ O1, float* __restrict__ O2)
{
    constexpr int TM = 128, TN = 128, BK = 32, K = DM, N = DM;

    const float* W  = (blockIdx.z == 0) ? W0 : (blockIdx.z == 1) ? W1 : W2;
    const float* bb = (blockIdx.z == 0) ? b0 : (blockIdx.z == 1) ? b1 : b2;
    float*       O  = (blockIdx.z == 0) ? O0 : (blockIdx.z == 1) ? O1 : O2;

    __shared__ float As[BK][TM + 4];
    __shared__ float Bs[BK][TN + 4];

    const int t  = threadIdx.x;
    const int m0 = blockIdx.y * TM;
    const int n0 = blockIdx.x * TN;

    const int lrow = t >> 3;        // 0..31 (+32 per pass)
    const int lk   = (t & 7) * 4;   // k offset within tile

    const int tx = t & 15;          // n group
    const int ty = t >> 4;          // m group

    float acc[8][8];
#pragma unroll
    for (int i = 0; i < 8; ++i)
#pragma unroll
        for (int j = 0; j < 8; ++j) acc[i][j] = 0.f;

    for (int k0 = 0; k0 < K; k0 += BK) {
        float4 av[4], wv[4];
#pragma unroll
        for (int p = 0; p < 4; ++p) {
            const int r = lrow + p * 32;
            av[p] = *(const float4*)(A + (size_t)(m0 + r) * K + k0 + lk);
            wv[p] = *(const float4*)(W + (size_t)(n0 + r) * K + k0 + lk);
        }
        __syncthreads();
#pragma unroll
        for (int p = 0; p < 4; ++p) {
            const int r = lrow + p * 32;
            As[lk + 0][r] = av[p].x; As[lk + 1][r] = av[p].y;
            As[lk + 2][r] = av[p].z; As[lk + 3][r] = av[p].w;
            Bs[lk + 0][r] = wv[p].x; Bs[lk + 1][r] = wv[p].y;
            Bs[lk + 2][r] = wv[p].z; Bs[lk + 3][r] = wv[p].w;
        }
        __syncthreads();
#pragma unroll
        for (int k = 0; k < BK; ++k) {
            const float4 a0 = *(const float4*)&As[k][ty * 8];
            const float4 a1 = *(const float4*)&As[k][ty * 8 + 4];
            const float4 w0 = *(const float4*)&Bs[k][tx * 8];
            const float4 w1 = *(const float4*)&Bs[k][tx * 8 + 4];
            const float am[8] = {a0.x, a0.y, a0.z, a0.w, a1.x, a1.y, a1.z, a1.w};
            const float bn[8] = {w0.x, w0.y, w0.z, w0.w, w1.x, w1.y, w1.z, w1.w};
#pragma unroll
            for (int i = 0; i < 8; ++i)
#pragma unroll
                for (int j = 0; j < 8; ++j)
                    acc[i][j] = fmaf(am[i], bn[j], acc[i][j]);
        }
    }

    const int n = n0 + tx * 8;
    const float4 bv0 = *(const float4*)(bb + n);
    const float4 bv1 = *(const float4*)(bb + n + 4);

    if (MODE == 0) {
#pragma unroll
        for (int r = 0; r < 8; ++r) {
            const int m = m0 + ty * 8 + r;
            float4 o0 = {acc[r][0] + bv0.x, acc[r][1] + bv0.y,
                         acc[r][2] + bv0.z, acc[r][3] + bv0.w};
            float4 o1 = {acc[r][4] + bv1.x, acc[r][5] + bv1.y,
                         acc[r][6] + bv1.z, acc[r][7] + bv1.w};
            *(float4*)(O + (size_t)m * N + n)     = o0;
            *(float4*)(O + (size_t)m * N + n + 4) = o1;
        }
    } else {
        const int h = n >> 6, d = n & 63;
#pragma unroll
        for (int r = 0; r < 8; ++r) {
            const int m = m0 + ty * 8 + r;
            const int b = m >> 11, s = m & (SQ - 1);
            const size_t off = ((size_t)(b * NH + h) * SQ + s) * DH + d;
            float4 o0 = {acc[r][0] + bv0.x, acc[r][1] + bv0.y,
                         acc[r][2] + bv0.z, acc[r][3] + bv0.w};
            float4 o1 = {acc[r][4] + bv1.x, acc[r][5] + bv1.y,
                         acc[r][6] + bv1.z, acc[r][7] + bv1.w};
            *(float4*)(O + off)     = o0;
            *(float4*)(O + off + 4) = o1;
        }
    }
}

// ---------------------------------------------------------------------------
// Sliding-window attention v2: one 64-lane wave per (b, h, query i).
// SCORE PHASE: lane = key (no per-key shuffle chain!). q staged in LDS,
// broadcast-read as float4; each lane dot-products its key's row serially.
// One 6-step shuffle reduction per QUERY (max, sum) instead of per key.
// PV PHASE: lane = dh index, p broadcast from LDS as float4, coalesced V.
// Writes the FULL attn row (band probs + zeros) -> no separate memset pass.
// ---------------------------------------------------------------------------
__global__ __launch_bounds__(64) void attn_win(
    const float* __restrict__ Q, const float* __restrict__ K,
    const float* __restrict__ V, float* __restrict__ attn,
    float* __restrict__ ctx)
{
    const int lane = threadIdx.x;
    const int i = blockIdx.x, h = blockIdx.y, b = blockIdx.z;
    const int bh = b * NH + h;

    const int j0 = max(i - WN, 0);
    const int j1 = min(i + WN, SQ - 1);
    const int nj = j1 - j0 + 1;          // 129..257

    const float* Kb = K + ((size_t)bh * SQ + j0) * DH;
    const float* Vb = V + ((size_t)bh * SQ + j0) * DH;

    __shared__ float qls[DH];
    __shared__ float pls[320];

    qls[lane] = Q[((size_t)bh * SQ + i) * DH + lane];
    __syncthreads();

    // ---- scores: lane owns key jj = sl*64 + lane ----
    float sc[5];
#pragma unroll
    for (int sl = 0; sl < 5; ++sl) {
        const int jj = sl * 64 + lane;
        float s = -1e30f;
        if (jj < nj) {
            const float4* kr = (const float4*)(Kb + (size_t)jj * DH);
            const float4* q4 = (const float4*)qls;
            float a0 = 0.f, a1 = 0.f, a2 = 0.f, a3 = 0.f;
#pragma unroll
            for (int d4 = 0; d4 < 16; ++d4) {
                const float4 kv = kr[d4];
                const float4 qv = q4[d4];    // LDS broadcast, conflict-free
                a0 = fmaf(qv.x, kv.x, a0);
                a1 = fmaf(qv.y, kv.y, a1);
                a2 = fmaf(qv.z, kv.z, a2);
                a3 = fmaf(qv.w, kv.w, a3);
            }
            s = ((a0 + a1) + (a2 + a3)) * 0.125f;   // 1/sqrt(64)
        }
        sc[sl] = s;
    }

    // ---- softmax (one wave-wide reduction per query) ----
    float mx = sc[0];
#pragma unroll
    for (int sl = 1; sl < 5; ++sl) mx = fmaxf(mx, sc[sl]);
    mx = fmaxf(mx, __shfl_xor(mx, 32)); mx = fmaxf(mx, __shfl_xor(mx, 16));
    mx = fmaxf(mx, __shfl_xor(mx, 8));  mx = fmaxf(mx, __shfl_xor(mx, 4));
    mx = fmaxf(mx, __shfl_xor(mx, 2));  mx = fmaxf(mx, __shfl_xor(mx, 1));

    float e[5], lsum = 0.f;
#pragma unroll
    for (int sl = 0; sl < 5; ++sl) { e[sl] = __expf(sc[sl] - mx); lsum += e[sl]; }
    lsum += __shfl_xor(lsum, 32); lsum += __shfl_xor(lsum, 16);
    lsum += __shfl_xor(lsum, 8);  lsum += __shfl_xor(lsum, 4);
    lsum += __shfl_xor(lsum, 2);  lsum += __shfl_xor(lsum, 1);
    const float inv = 1.0f / lsum;

#pragma unroll
    for (int sl = 0; sl < 5; ++sl) pls[sl * 64 + lane] = e[sl] * inv;
    __syncthreads();

    // ---- full attn row: float4 stores (band probs + explicit zeros) ----
    float* arow = attn + ((size_t)bh * SQ + i) * SQ;
#pragma unroll
    for (int s8 = 0; s8 < 8; ++s8) {
        const int j  = s8 * 256 + lane * 4;
        const int jj = j - j0;
        float4 o;
        {
            const int t0 = jj + 0, t1 = jj + 1, t2 = jj + 2, t3 = jj + 3;
            const int c0 = t0 < 0 ? 0 : (t0 > 319 ? 319 : t0);
            const int c1 = t1 < 0 ? 0 : (t1 > 319 ? 319 : t1);
            const int c2 = t2 < 0 ? 0 : (t2 > 319 ? 319 : t2);
            const int c3 = t3 < 0 ? 0 : (t3 > 319 ? 319 : t3);
            o.x = ((unsigned)t0 < (unsigned)nj) ? pls[c0] : 0.f;
            o.y = ((unsigned)t1 < (unsigned)nj) ? pls[c1] : 0.f;
            o.z = ((unsigned)t2 < (unsigned)nj) ? pls[c2] : 0.f;
            o.w = ((unsigned)t3 < (unsigned)nj) ? pls[c3] : 0.f;
        }
        *(float4*)(arow + j) = o;
    }

    // ---- ctx = P @ V  (lane = dh index, coalesced V, float4 p reads) ----
    float acc = 0.f;
    int j = 0;
    for (; j + 4 <= nj; j += 4) {
        const float4 p = *(const float4*)&pls[j];
        acc = fmaf(p.x, Vb[(size_t)(j + 0) * DH + lane], acc);
        acc = fmaf(p.y, Vb[(size_t)(j + 1) * DH + lane], acc);
        acc = fmaf(p.z, Vb[(size_t)(j + 2) * DH + lane], acc);
        acc = fmaf(p.w, Vb[(size_t)(j + 3) * DH + lane], acc);
    }
    for (; j < nj; ++j)
        acc = fmaf(pls[j], Vb[(size_t)j * DH + lane], acc);

    // ctx layout [B,S,D] so the out-projection is a plain GEMM
    ctx[((size_t)(b * SQ + i)) * DM + h * DH + lane] = acc;
}

// ---------------------------------------------------------------------------
extern "C" void kernel_launch(void* const* d_in, const int* in_sizes, int n_in,
                              void* d_out, int out_size, void* d_ws, size_t ws_size,
                              hipStream_t stream)
{
    const float* x  = (const float*)d_in[0];
    const float* Wq = (const float*)d_in[1];
    const float* bq = (const float*)d_in[2];
    const float* Wk = (const float*)d_in[3];
    const float* bk = (const float*)d_in[4];
    const float* Wv = (const float*)d_in[5];
    const float* bv = (const float*)d_in[6];
    const float* Wo = (const float*)d_in[7];
    const float* bo = (const float*)d_in[8];

    float* out  = (float*)d_out;
    float* attn = out + (size_t)NB * SQ * DM;

    const size_t qkv = (size_t)NB * NH * SQ * DH;
    float* Qw = (float*)d_ws;
    float* Kw = Qw + qkv;
    float* Vw = Kw + qkv;
    float* Cw = Vw + qkv;

    gemm_xwt<1><<<dim3(DM / 128, (NB * SQ) / 128, 3), dim3(256), 0, stream>>>(
        x, Wq, Wk, Wv, bq, bk, bv, Qw, Kw, Vw);

    attn_win<<<dim3(SQ, NH, NB), dim3(64), 0, stream>>>(Qw, Kw, Vw, attn, Cw);

    gemm_xwt<0><<<dim3(DM / 128, (NB * SQ) / 128, 1), dim3(256), 0, stream>>>(
        Cw, Wo, Wo, Wo, bo, bo, bo, out, out, out);
}

// Round 3
// 1140.768 us; speedup vs baseline: 1.7492x; 1.3945x over previous
//
#include <hip/hip_runtime.h>
#include <cstddef>

#define NB 2
#define NH 16
#define SQ 2048
#define DM 1024
#define DH 64
#define WN 128

// ---------------------------------------------------------------------------
// fp32 tiled GEMM: C = A @ W^T + bias      A:[M,K] row-major, W:[N,K] row-major
// MODE 0: O[m*N + n]          (plain row-major, used for out-projection)
// MODE 1: O[((b*NH + n/64)*SQ + s)*64 + (n%64)]   (QKV -> [B,H,S,dh] layout)
// ---------------------------------------------------------------------------
template <int MODE>
__global__ __launch_bounds__(256) void gemm_xwt(
    const float* __restrict__ A,
    const float* __restrict__ W0, const float* __restrict__ W1,
    const float* __restrict__ W2,
    const float* __restrict__ b0, const float* __restrict__ b1,
    const float* __restrict__ b2,
    float* __restrict__ O0, float* __restrict__ O1, float* __restrict__ O2)
{
    constexpr int TM = 128, TN = 128, BK = 32, K = DM, N = DM;

    const float* W  = (blockIdx.z == 0) ? W0 : (blockIdx.z == 1) ? W1 : W2;
    const float* bb = (blockIdx.z == 0) ? b0 : (blockIdx.z == 1) ? b1 : b2;
    float*       O  = (blockIdx.z == 0) ? O0 : (blockIdx.z == 1) ? O1 : O2;

    __shared__ float As[BK][TM + 4];
    __shared__ float Bs[BK][TN + 4];

    const int t  = threadIdx.x;
    const int m0 = blockIdx.y * TM;
    const int n0 = blockIdx.x * TN;

    const int lrow = t >> 3;
    const int lk   = (t & 7) * 4;
    const int tx = t & 15;
    const int ty = t >> 4;

    float acc[8][8];
#pragma unroll
    for (int i = 0; i < 8; ++i)
#pragma unroll
        for (int j = 0; j < 8; ++j) acc[i][j] = 0.f;

    for (int k0 = 0; k0 < K; k0 += BK) {
        float4 av[4], wv[4];
#pragma unroll
        for (int p = 0; p < 4; ++p) {
            const int r = lrow + p * 32;
            av[p] = *(const float4*)(A + (size_t)(m0 + r) * K + k0 + lk);
            wv[p] = *(const float4*)(W + (size_t)(n0 + r) * K + k0 + lk);
        }
        __syncthreads();
#pragma unroll
        for (int p = 0; p < 4; ++p) {
            const int r = lrow + p * 32;
            As[lk + 0][r] = av[p].x; As[lk + 1][r] = av[p].y;
            As[lk + 2][r] = av[p].z; As[lk + 3][r] = av[p].w;
            Bs[lk + 0][r] = wv[p].x; Bs[lk + 1][r] = wv[p].y;
            Bs[lk + 2][r] = wv[p].z; Bs[lk + 3][r] = wv[p].w;
        }
        __syncthreads();
#pragma unroll
        for (int k = 0; k < BK; ++k) {
            const float4 a0 = *(const float4*)&As[k][ty * 8];
            const float4 a1 = *(const float4*)&As[k][ty * 8 + 4];
            const float4 w0 = *(const float4*)&Bs[k][tx * 8];
            const float4 w1 = *(const float4*)&Bs[k][tx * 8 + 4];
            const float am[8] = {a0.x, a0.y, a0.z, a0.w, a1.x, a1.y, a1.z, a1.w};
            const float bn[8] = {w0.x, w0.y, w0.z, w0.w, w1.x, w1.y, w1.z, w1.w};
#pragma unroll
            for (int i = 0; i < 8; ++i)
#pragma unroll
                for (int j = 0; j < 8; ++j)
                    acc[i][j] = fmaf(am[i], bn[j], acc[i][j]);
        }
    }

    const int n = n0 + tx * 8;
    const float4 bv0 = *(const float4*)(bb + n);
    const float4 bv1 = *(const float4*)(bb + n + 4);

    if (MODE == 0) {
#pragma unroll
        for (int r = 0; r < 8; ++r) {
            const int m = m0 + ty * 8 + r;
            float4 o0 = {acc[r][0] + bv0.x, acc[r][1] + bv0.y,
                         acc[r][2] + bv0.z, acc[r][3] + bv0.w};
            float4 o1 = {acc[r][4] + bv1.x, acc[r][5] + bv1.y,
                         acc[r][6] + bv1.z, acc[r][7] + bv1.w};
            *(float4*)(O + (size_t)m * N + n)     = o0;
            *(float4*)(O + (size_t)m * N + n + 4) = o1;
        }
    } else {
        const int h = n >> 6, d = n & 63;
#pragma unroll
        for (int r = 0; r < 8; ++r) {
            const int m = m0 + ty * 8 + r;
            const int b = m >> 11, s = m & (SQ - 1);
            const size_t off = ((size_t)(b * NH + h) * SQ + s) * DH + d;
            float4 o0 = {acc[r][0] + bv0.x, acc[r][1] + bv0.y,
                         acc[r][2] + bv0.z, acc[r][3] + bv0.w};
            float4 o1 = {acc[r][4] + bv1.x, acc[r][5] + bv1.y,
                         acc[r][6] + bv1.z, acc[r][7] + bv1.w};
            *(float4*)(O + off)     = o0;
            *(float4*)(O + off + 4) = o1;
        }
    }
}

// ---------------------------------------------------------------------------
// Sliding-window attention v3: query-tiled.
// Block = 320 threads (5 waves), TQ = 16 queries, padded key window = 320.
// Thread j owns key row (wo+j) in REGISTERS; scores for all 16 queries reuse
// it (K fetched once per tile, not once per query). Scores -> LDS P[16][320],
// wave-cooperative softmax, float4 attn-row writes, float4 PV with 16-lane
// d-groups and 4 independent accumulators.
// Valid window per query q (uniform): q <= j <= q+256.
// ---------------------------------------------------------------------------
__global__ __launch_bounds__(320) void attn_win(
    const float* __restrict__ Q, const float* __restrict__ K,
    const float* __restrict__ V, float* __restrict__ attn,
    float* __restrict__ ctx)
{
    const int tid = threadIdx.x;
    const int h = blockIdx.y, b = blockIdx.z;
    const int bh = b * NH + h;
    const int i0 = blockIdx.x * 16;
    const int wo = i0 - WN;                 // window origin (may be negative)

    __shared__ float Qs[16][DH];            // 4 KB
    __shared__ float P[16][320];            // 20 KB

    // ---- stage Q tile ----
    for (int t = tid; t < 16 * DH; t += 320) {
        const int q = t >> 6, d = t & 63;
        Qs[q][d] = Q[((size_t)bh * SQ + i0 + q) * DH + d];
    }

    // ---- own one K row in registers ----
    const int jg = wo + tid;                // global key index of this thread
    float4 kreg[16];
    if (jg >= 0 && jg < SQ) {
        const float4* kr = (const float4*)(K + ((size_t)bh * SQ + jg) * DH);
#pragma unroll
        for (int d4 = 0; d4 < 16; ++d4) kreg[d4] = kr[d4];
    } else {
#pragma unroll
        for (int d4 = 0; d4 < 16; ++d4) kreg[d4] = make_float4(0.f, 0.f, 0.f, 0.f);
    }
    __syncthreads();

    // ---- scores: 16 queries x this thread's key ----
#pragma unroll
    for (int q = 0; q < 16; ++q) {
        const float4* q4 = (const float4*)Qs[q];
        float a0 = 0.f, a1 = 0.f, a2 = 0.f, a3 = 0.f;
#pragma unroll
        for (int d4 = 0; d4 < 16; ++d4) {
            const float4 qv = q4[d4];       // LDS broadcast
            a0 = fmaf(qv.x, kreg[d4].x, a0);
            a1 = fmaf(qv.y, kreg[d4].y, a1);
            a2 = fmaf(qv.z, kreg[d4].z, a2);
            a3 = fmaf(qv.w, kreg[d4].w, a3);
        }
        const float s = ((a0 + a1) + (a2 + a3)) * 0.125f;  // 1/sqrt(64)
        const bool valid = ((unsigned)(tid - q) <= 256u) && (jg >= 0) && (jg < SQ);
        P[q][tid] = valid ? s : -1e30f;
    }
    __syncthreads();

    // ---- softmax per query (wave w handles q = w, w+5, ...) ----
    const int lane = tid & 63, w = tid >> 6;
    for (int q = w; q < 16; q += 5) {
        float v0 = P[q][lane],       v1 = P[q][lane + 64],
              v2 = P[q][lane + 128], v3 = P[q][lane + 192],
              v4 = P[q][lane + 256];
        float m = fmaxf(fmaxf(fmaxf(v0, v1), fmaxf(v2, v3)), v4);
        m = fmaxf(m, __shfl_xor(m, 32)); m = fmaxf(m, __shfl_xor(m, 16));
        m = fmaxf(m, __shfl_xor(m, 8));  m = fmaxf(m, __shfl_xor(m, 4));
        m = fmaxf(m, __shfl_xor(m, 2));  m = fmaxf(m, __shfl_xor(m, 1));
        float e0 = __expf(v0 - m), e1 = __expf(v1 - m), e2 = __expf(v2 - m),
              e3 = __expf(v3 - m), e4 = __expf(v4 - m);
        float sum = ((e0 + e1) + (e2 + e3)) + e4;
        sum += __shfl_xor(sum, 32); sum += __shfl_xor(sum, 16);
        sum += __shfl_xor(sum, 8);  sum += __shfl_xor(sum, 4);
        sum += __shfl_xor(sum, 2);  sum += __shfl_xor(sum, 1);
        const float inv = 1.0f / sum;
        P[q][lane]       = e0 * inv;
        P[q][lane + 64]  = e1 * inv;
        P[q][lane + 128] = e2 * inv;
        P[q][lane + 192] = e3 * inv;
        P[q][lane + 256] = e4 * inv;
    }
    __syncthreads();

    // ---- full attn rows: 16 rows x 512 float4 ----
    for (int idx = tid; idx < 16 * 512; idx += 320) {
        const int q  = idx >> 9;
        const int c4 = (idx & 511) << 2;
        const int jj = c4 - wo;             // window-relative index of col c4
        float4 o;
        const unsigned u0 = (unsigned)(jj + 0 - q);
        const unsigned u1 = (unsigned)(jj + 1 - q);
        const unsigned u2 = (unsigned)(jj + 2 - q);
        const unsigned u3 = (unsigned)(jj + 3 - q);
        o.x = (u0 <= 256u) ? P[q][jj + 0] : 0.f;
        o.y = (u1 <= 256u) ? P[q][jj + 1] : 0.f;
        o.z = (u2 <= 256u) ? P[q][jj + 2] : 0.f;
        o.w = (u3 <= 256u) ? P[q][jj + 3] : 0.f;
        *(float4*)(attn + ((size_t)bh * SQ + i0 + q) * SQ + c4) = o;
    }

    // ---- PV: out[q, d..d+3] ; group g = one query, 16 lanes x float4 over d
    const int dgrp = tid & 15, g = tid >> 4;    // g in 0..19
    if (g < 16) {
        const int q = g;
        const int d = dgrp * 4;
        const float* Vrow = V + (size_t)bh * SQ * DH + d;
        float4 acc0 = {0,0,0,0}, acc1 = {0,0,0,0},
               acc2 = {0,0,0,0}, acc3 = {0,0,0,0};
        int j = q;
        for (; j + 4 <= q + 257; j += 4) {
            const int g0 = wo + j,     g1 = wo + j + 1,
                      g2 = wo + j + 2, g3 = wo + j + 3;
            const int c0 = g0 < 0 ? 0 : (g0 >= SQ ? SQ - 1 : g0);
            const int c1 = g1 < 0 ? 0 : (g1 >= SQ ? SQ - 1 : g1);
            const int c2 = g2 < 0 ? 0 : (g2 >= SQ ? SQ - 1 : g2);
            const int c3 = g3 < 0 ? 0 : (g3 >= SQ ? SQ - 1 : g3);
            const float p0 = P[q][j + 0], p1 = P[q][j + 1],
                        p2 = P[q][j + 2], p3 = P[q][j + 3];
            const float4 v0 = *(const float4*)(Vrow + (size_t)c0 * DH);
            const float4 v1 = *(const float4*)(Vrow + (size_t)c1 * DH);
            const float4 v2 = *(const float4*)(Vrow + (size_t)c2 * DH);
            const float4 v3 = *(const float4*)(Vrow + (size_t)c3 * DH);
            acc0.x = fmaf(p0, v0.x, acc0.x); acc0.y = fmaf(p0, v0.y, acc0.y);
            acc0.z = fmaf(p0, v0.z, acc0.z); acc0.w = fmaf(p0, v0.w, acc0.w);
            acc1.x = fmaf(p1, v1.x, acc1.x); acc1.y = fmaf(p1, v1.y, acc1.y);
            acc1.z = fmaf(p1, v1.z, acc1.z); acc1.w = fmaf(p1, v1.w, acc1.w);
            acc2.x = fmaf(p2, v2.x, acc2.x); acc2.y = fmaf(p2, v2.y, acc2.y);
            acc2.z = fmaf(p2, v2.z, acc2.z); acc2.w = fmaf(p2, v2.w, acc2.w);
            acc3.x = fmaf(p3, v3.x, acc3.x); acc3.y = fmaf(p3, v3.y, acc3.y);
            acc3.z = fmaf(p3, v3.z, acc3.z); acc3.w = fmaf(p3, v3.w, acc3.w);
        }
        // tail (257 = 64*4 + 1)
        {
            const int gj = wo + j;
            const int cj = gj < 0 ? 0 : (gj >= SQ ? SQ - 1 : gj);
            const float pj = P[q][j];
            const float4 vj = *(const float4*)(Vrow + (size_t)cj * DH);
            acc0.x = fmaf(pj, vj.x, acc0.x); acc0.y = fmaf(pj, vj.y, acc0.y);
            acc0.z = fmaf(pj, vj.z, acc0.z); acc0.w = fmaf(pj, vj.w, acc0.w);
        }
        float4 o;
        o.x = (acc0.x + acc1.x) + (acc2.x + acc3.x);
        o.y = (acc0.y + acc1.y) + (acc2.y + acc3.y);
        o.z = (acc0.z + acc1.z) + (acc2.z + acc3.z);
        o.w = (acc0.w + acc1.w) + (acc2.w + acc3.w);
        // ctx layout [B,S,D] so the out-projection is a plain GEMM
        *(float4*)(ctx + ((size_t)(b * SQ + i0 + q)) * DM + h * DH + d) = o;
    }
}

// ---------------------------------------------------------------------------
extern "C" void kernel_launch(void* const* d_in, const int* in_sizes, int n_in,
                              void* d_out, int out_size, void* d_ws, size_t ws_size,
                              hipStream_t stream)
{
    const float* x  = (const float*)d_in[0];
    const float* Wq = (const float*)d_in[1];
    const float* bq = (const float*)d_in[2];
    const float* Wk = (const float*)d_in[3];
    const float* bk = (const float*)d_in[4];
    const float* Wv = (const float*)d_in[5];
    const float* bv = (const float*)d_in[6];
    const float* Wo = (const float*)d_in[7];
    const float* bo = (const float*)d_in[8];

    float* out  = (float*)d_out;
    float* attn = out + (size_t)NB * SQ * DM;

    const size_t qkv = (size_t)NB * NH * SQ * DH;
    float* Qw = (float*)d_ws;
    float* Kw = Qw + qkv;
    float* Vw = Kw + qkv;
    float* Cw = Vw + qkv;

    gemm_xwt<1><<<dim3(DM / 128, (NB * SQ) / 128, 3), dim3(256), 0, stream>>>(
        x, Wq, Wk, Wv, bq, bk, bv, Qw, Kw, Vw);

    attn_win<<<dim3(SQ / 16, NH, NB), dim3(320), 0, stream>>>(Qw, Kw, Vw, attn, Cw);

    gemm_xwt<0><<<dim3(DM / 128, (NB * SQ) / 128, 1), dim3(256), 0, stream>>>(
        Cw, Wo, Wo, Wo, bo, bo, bo, out, out, out);
}

// Round 4
// 793.504 us; speedup vs baseline: 2.5147x; 1.4376x over previous
//
#include <hip/hip_runtime.h>
#include <cstddef>

#define NB 2
#define NH 16
#define SQ 2048
#define DM 1024
#define DH 64
#define WN 128

using half8  = __attribute__((ext_vector_type(8))) _Float16;
using half4  = __attribute__((ext_vector_type(4))) _Float16;
using floatx4 = __attribute__((ext_vector_type(4))) float;

__device__ __forceinline__ void gl_lds16(const _Float16* g, _Float16* l) {
    __builtin_amdgcn_global_load_lds(
        (const __attribute__((address_space(1))) void*)g,
        (__attribute__((address_space(3))) void*)l, 16, 0, 0);
}

// ---------------------------------------------------------------------------
// fp32 -> fp16 converters
// ---------------------------------------------------------------------------
__global__ __launch_bounds__(256) void cvt1(const float* __restrict__ s,
                                            _Float16* __restrict__ d, int n8)
{
    int idx = blockIdx.x * 256 + threadIdx.x;
    if (idx < n8) {
        const float4 a = ((const float4*)s)[idx * 2];
        const float4 b = ((const float4*)s)[idx * 2 + 1];
        half8 h;
        h[0] = (_Float16)a.x; h[1] = (_Float16)a.y;
        h[2] = (_Float16)a.z; h[3] = (_Float16)a.w;
        h[4] = (_Float16)b.x; h[5] = (_Float16)b.y;
        h[6] = (_Float16)b.z; h[7] = (_Float16)b.w;
        ((half8*)d)[idx] = h;
    }
}

__global__ __launch_bounds__(256) void cvt4(
    const float* __restrict__ s0, const float* __restrict__ s1,
    const float* __restrict__ s2, const float* __restrict__ s3,
    _Float16* __restrict__ d0, _Float16* __restrict__ d1,
    _Float16* __restrict__ d2, _Float16* __restrict__ d3, int n8)
{
    const float* s = (blockIdx.y == 0) ? s0 : (blockIdx.y == 1) ? s1
                   : (blockIdx.y == 2) ? s2 : s3;
    _Float16*   d = (blockIdx.y == 0) ? d0 : (blockIdx.y == 1) ? d1
                   : (blockIdx.y == 2) ? d2 : d3;
    int idx = blockIdx.x * 256 + threadIdx.x;
    if (idx < n8) {
        const float4 a = ((const float4*)s)[idx * 2];
        const float4 b = ((const float4*)s)[idx * 2 + 1];
        half8 h;
        h[0] = (_Float16)a.x; h[1] = (_Float16)a.y;
        h[2] = (_Float16)a.z; h[3] = (_Float16)a.w;
        h[4] = (_Float16)b.x; h[5] = (_Float16)b.y;
        h[6] = (_Float16)b.z; h[7] = (_Float16)b.w;
        ((half8*)d)[idx] = h;
    }
}

// ---------------------------------------------------------------------------
// fp16 MFMA GEMM (m97 structure): C = A @ W^T + bias
// A:[M,K] fp16 row-major, W:[N,K] fp16 row-major (nn.Linear layout).
// 128x128 tile, 4 waves x (4x4) mfma_f32_16x16x32_f16, BK=64.
// global_load_lds width=16 staging; XOR-swizzled LDS chunks (row stride is
// 128 B, so without swizzle every frag ds_read_b128 would be 16-way bank
// conflicted; swizzle: chunk' = chunk ^ (row&7) on BOTH stage & read sides).
// OUT_HALF=1 -> fp16 output (QKV path), 0 -> fp32 output (final out).
// blockIdx.z selects {W0,b0,O0}/{W1,b1,O1}/{W2,b2,O2}.
// ---------------------------------------------------------------------------
template <int OUT_HALF>
__global__ __launch_bounds__(256) void gemm_h(
    const _Float16* __restrict__ A,
    const _Float16* __restrict__ W0, const _Float16* __restrict__ W1,
    const _Float16* __restrict__ W2,
    const float* __restrict__ b0, const float* __restrict__ b1,
    const float* __restrict__ b2,
    void* __restrict__ O0, void* __restrict__ O1, void* __restrict__ O2)
{
    constexpr int K = DM, N = DM, BK = 64;

    const _Float16* Wp = (blockIdx.z == 0) ? W0 : (blockIdx.z == 1) ? W1 : W2;
    const float*    bb = (blockIdx.z == 0) ? b0 : (blockIdx.z == 1) ? b1 : b2;
    void*           Op = (blockIdx.z == 0) ? O0 : (blockIdx.z == 1) ? O1 : O2;

    __shared__ _Float16 Asl[128 * BK];   // 16 KB
    __shared__ _Float16 Bsl[128 * BK];   // 16 KB

    const int tid  = threadIdx.x;
    const int lane = tid & 63;
    const int w    = tid >> 6;          // wave 0..3
    const int wm   = w & 1, wn = w >> 1;
    const int m0   = blockIdx.y * 128;
    const int n0   = blockIdx.x * 128;

    const int l8 = lane >> 3;           // row within 8-row group
    const int lc = lane & 7;            // 16B chunk within row

    floatx4 acc[4][4];
#pragma unroll
    for (int t = 0; t < 4; ++t)
#pragma unroll
        for (int u = 0; u < 4; ++u) acc[t][u] = (floatx4){0.f, 0.f, 0.f, 0.f};

    for (int k0 = 0; k0 < K; k0 += BK) {
        __syncthreads();                 // prior iter's LDS reads done
#pragma unroll
        for (int i = 0; i < 4; ++i) {
            const int r  = w * 8 + l8 + i * 32;      // tile row 0..127
            const int ca = lc ^ (r & 7);             // swizzled chunk
            gl_lds16(A  + (size_t)(m0 + r) * K + k0 + ca * 8,
                     Asl + r * BK + lc * 8);
            gl_lds16(Wp + (size_t)(n0 + r) * K + k0 + ca * 8,
                     Bsl + r * BK + lc * 8);
        }
        __syncthreads();                 // drain global_load_lds
#pragma unroll
        for (int kk = 0; kk < BK; kk += 32) {
            half8 af[4], bf[4];
            const int q = (kk >> 3) + (lane >> 4);   // chunk idx 0..7
#pragma unroll
            for (int t = 0; t < 4; ++t) {
                const int ra = wm * 64 + t * 16 + (lane & 15);
                af[t] = *(const half8*)(Asl + ra * BK + ((q ^ (ra & 7)) << 3));
                const int rb = wn * 64 + t * 16 + (lane & 15);
                bf[t] = *(const half8*)(Bsl + rb * BK + ((q ^ (rb & 7)) << 3));
            }
#pragma unroll
            for (int t = 0; t < 4; ++t)
#pragma unroll
                for (int u = 0; u < 4; ++u)
                    acc[t][u] = __builtin_amdgcn_mfma_f32_16x16x32_f16(
                        af[t], bf[u], acc[t][u], 0, 0, 0);
        }
    }

    // epilogue: C/D layout col=lane&15, row=(lane>>4)*4+reg
    const int col0 = n0 + wn * 64 + (lane & 15);
    const int row0 = m0 + wm * 64 + ((lane >> 4) << 2);
#pragma unroll
    for (int u = 0; u < 4; ++u) {
        const int n = col0 + u * 16;
        const float bias = bb[n];
#pragma unroll
        for (int t = 0; t < 4; ++t) {
            const int m = row0 + t * 16;
#pragma unroll
            for (int r = 0; r < 4; ++r) {
                const float v = acc[t][u][r] + bias;
                if (OUT_HALF)
                    ((_Float16*)Op)[(size_t)(m + r) * N + n] = (_Float16)v;
                else
                    ((float*)Op)[(size_t)(m + r) * N + n] = v;
            }
        }
    }
}

// ---------------------------------------------------------------------------
// Sliding-window attention v4: query-tiled, fp16 Q/K/V in [B,S,D] layout.
// Block = 320 threads (5 waves), TQ = 16 queries, padded key window = 320.
// Math in fp32; attn rows written fp32; ctx written fp16 [B,S,D].
// ---------------------------------------------------------------------------
__global__ __launch_bounds__(320) void attn_win(
    const _Float16* __restrict__ Q, const _Float16* __restrict__ K,
    const _Float16* __restrict__ V, float* __restrict__ attn,
    _Float16* __restrict__ ctx)
{
    const int tid = threadIdx.x;
    const int h = blockIdx.y, b = blockIdx.z;
    const int bh = b * NH + h;
    const int i0 = blockIdx.x * 16;
    const int wo = i0 - WN;                 // window origin (may be negative)

    __shared__ float Qs[16][DH];            // 4 KB
    __shared__ float P[16][320];            // 20 KB

    // ---- stage Q tile (fp16 -> fp32) ----
    for (int t = tid; t < 16 * DH; t += 320) {
        const int q = t >> 6, d = t & 63;
        Qs[q][d] = (float)Q[((size_t)(b * SQ + i0 + q)) * DM + h * DH + d];
    }

    // ---- own one K row in registers (fp16 load, fp32 regs) ----
    const int jg = wo + tid;                // global key index of this thread
    float4 kreg[16];
    if (jg >= 0 && jg < SQ) {
        const half8* kr = (const half8*)(K + ((size_t)(b * SQ + jg)) * DM + h * DH);
#pragma unroll
        for (int d8 = 0; d8 < 8; ++d8) {
            const half8 kh = kr[d8];
            kreg[d8 * 2]     = make_float4((float)kh[0], (float)kh[1],
                                           (float)kh[2], (float)kh[3]);
            kreg[d8 * 2 + 1] = make_float4((float)kh[4], (float)kh[5],
                                           (float)kh[6], (float)kh[7]);
        }
    } else {
#pragma unroll
        for (int d4 = 0; d4 < 16; ++d4) kreg[d4] = make_float4(0.f, 0.f, 0.f, 0.f);
    }
    __syncthreads();

    // ---- scores: 16 queries x this thread's key ----
#pragma unroll
    for (int q = 0; q < 16; ++q) {
        const float4* q4 = (const float4*)Qs[q];
        float a0 = 0.f, a1 = 0.f, a2 = 0.f, a3 = 0.f;
#pragma unroll
        for (int d4 = 0; d4 < 16; ++d4) {
            const float4 qv = q4[d4];       // LDS broadcast
            a0 = fmaf(qv.x, kreg[d4].x, a0);
            a1 = fmaf(qv.y, kreg[d4].y, a1);
            a2 = fmaf(qv.z, kreg[d4].z, a2);
            a3 = fmaf(qv.w, kreg[d4].w, a3);
        }
        const float s = ((a0 + a1) + (a2 + a3)) * 0.125f;  // 1/sqrt(64)
        const bool valid = ((unsigned)(tid - q) <= 256u) && (jg >= 0) && (jg < SQ);
        P[q][tid] = valid ? s : -1e30f;
    }
    __syncthreads();

    // ---- softmax per query (wave w handles q = w, w+5, ...) ----
    const int lane = tid & 63, w = tid >> 6;
    for (int q = w; q < 16; q += 5) {
        float v0 = P[q][lane],       v1 = P[q][lane + 64],
              v2 = P[q][lane + 128], v3 = P[q][lane + 192],
              v4 = P[q][lane + 256];
        float m = fmaxf(fmaxf(fmaxf(v0, v1), fmaxf(v2, v3)), v4);
        m = fmaxf(m, __shfl_xor(m, 32)); m = fmaxf(m, __shfl_xor(m, 16));
        m = fmaxf(m, __shfl_xor(m, 8));  m = fmaxf(m, __shfl_xor(m, 4));
        m = fmaxf(m, __shfl_xor(m, 2));  m = fmaxf(m, __shfl_xor(m, 1));
        float e0 = __expf(v0 - m), e1 = __expf(v1 - m), e2 = __expf(v2 - m),
              e3 = __expf(v3 - m), e4 = __expf(v4 - m);
        float sum = ((e0 + e1) + (e2 + e3)) + e4;
        sum += __shfl_xor(sum, 32); sum += __shfl_xor(sum, 16);
        sum += __shfl_xor(sum, 8);  sum += __shfl_xor(sum, 4);
        sum += __shfl_xor(sum, 2);  sum += __shfl_xor(sum, 1);
        const float inv = 1.0f / sum;
        P[q][lane]       = e0 * inv;
        P[q][lane + 64]  = e1 * inv;
        P[q][lane + 128] = e2 * inv;
        P[q][lane + 192] = e3 * inv;
        P[q][lane + 256] = e4 * inv;
    }
    __syncthreads();

    // ---- full attn rows: 16 rows x 512 float4 (band probs + zeros) ----
    for (int idx = tid; idx < 16 * 512; idx += 320) {
        const int q  = idx >> 9;
        const int c4 = (idx & 511) << 2;
        const int jj = c4 - wo;
        float4 o;
        const unsigned u0 = (unsigned)(jj + 0 - q);
        const unsigned u1 = (unsigned)(jj + 1 - q);
        const unsigned u2 = (unsigned)(jj + 2 - q);
        const unsigned u3 = (unsigned)(jj + 3 - q);
        o.x = (u0 <= 256u) ? P[q][jj + 0] : 0.f;
        o.y = (u1 <= 256u) ? P[q][jj + 1] : 0.f;
        o.z = (u2 <= 256u) ? P[q][jj + 2] : 0.f;
        o.w = (u3 <= 256u) ? P[q][jj + 3] : 0.f;
        *(float4*)(attn + ((size_t)bh * SQ + i0 + q) * SQ + c4) = o;
    }

    // ---- PV: group g = one query, 16 lanes x 4 d's; fp16 V ----
    const int dgrp = tid & 15, g = tid >> 4;    // g in 0..19
    if (g < 16) {
        const int q = g;
        const int d = dgrp * 4;
        const _Float16* Vrow = V + (size_t)(b * SQ) * DM + h * DH + d;
        float4 acc0 = {0,0,0,0}, acc1 = {0,0,0,0},
               acc2 = {0,0,0,0}, acc3 = {0,0,0,0};
        int j = q;
        for (; j + 4 <= q + 257; j += 4) {
            const int g0 = wo + j,     g1 = wo + j + 1,
                      g2 = wo + j + 2, g3 = wo + j + 3;
            const int c0 = g0 < 0 ? 0 : (g0 >= SQ ? SQ - 1 : g0);
            const int c1 = g1 < 0 ? 0 : (g1 >= SQ ? SQ - 1 : g1);
            const int c2 = g2 < 0 ? 0 : (g2 >= SQ ? SQ - 1 : g2);
            const int c3 = g3 < 0 ? 0 : (g3 >= SQ ? SQ - 1 : g3);
            const float p0 = P[q][j + 0], p1 = P[q][j + 1],
                        p2 = P[q][j + 2], p3 = P[q][j + 3];
            const half4 h0 = *(const half4*)(Vrow + (size_t)c0 * DM);
            const half4 h1 = *(const half4*)(Vrow + (size_t)c1 * DM);
            const half4 h2 = *(const half4*)(Vrow + (size_t)c2 * DM);
            const half4 h3 = *(const half4*)(Vrow + (size_t)c3 * DM);
            acc0.x = fmaf(p0, (float)h0[0], acc0.x); acc0.y = fmaf(p0, (float)h0[1], acc0.y);
            acc0.z = fmaf(p0, (float)h0[2], acc0.z); acc0.w = fmaf(p0, (float)h0[3], acc0.w);
            acc1.x = fmaf(p1, (float)h1[0], acc1.x); acc1.y = fmaf(p1, (float)h1[1], acc1.y);
            acc1.z = fmaf(p1, (float)h1[2], acc1.z); acc1.w = fmaf(p1, (float)h1[3], acc1.w);
            acc2.x = fmaf(p2, (float)h2[0], acc2.x); acc2.y = fmaf(p2, (float)h2[1], acc2.y);
            acc2.z = fmaf(p2, (float)h2[2], acc2.z); acc2.w = fmaf(p2, (float)h2[3], acc2.w);
            acc3.x = fmaf(p3, (float)h3[0], acc3.x); acc3.y = fmaf(p3, (float)h3[1], acc3.y);
            acc3.z = fmaf(p3, (float)h3[2], acc3.z); acc3.w = fmaf(p3, (float)h3[3], acc3.w);
        }
        {   // tail (257 = 64*4 + 1)
            const int gj = wo + j;
            const int cj = gj < 0 ? 0 : (gj >= SQ ? SQ - 1 : gj);
            const float pj = P[q][j];
            const half4 hj = *(const half4*)(Vrow + (size_t)cj * DM);
            acc0.x = fmaf(pj, (float)hj[0], acc0.x); acc0.y = fmaf(pj, (float)hj[1], acc0.y);
            acc0.z = fmaf(pj, (float)hj[2], acc0.z); acc0.w = fmaf(pj, (float)hj[3], acc0.w);
        }
        half4 hv;
        hv[0] = (_Float16)((acc0.x + acc1.x) + (acc2.x + acc3.x));
        hv[1] = (_Float16)((acc0.y + acc1.y) + (acc2.y + acc3.y));
        hv[2] = (_Float16)((acc0.z + acc1.z) + (acc2.z + acc3.z));
        hv[3] = (_Float16)((acc0.w + acc1.w) + (acc2.w + acc3.w));
        *(half4*)(ctx + ((size_t)(b * SQ + i0 + q)) * DM + h * DH + d) = hv;
    }
}

// ---------------------------------------------------------------------------
extern "C" void kernel_launch(void* const* d_in, const int* in_sizes, int n_in,
                              void* d_out, int out_size, void* d_ws, size_t ws_size,
                              hipStream_t stream)
{
    const float* x  = (const float*)d_in[0];
    const float* Wq = (const float*)d_in[1];
    const float* bq = (const float*)d_in[2];
    const float* Wk = (const float*)d_in[3];
    const float* bk = (const float*)d_in[4];
    const float* Wv = (const float*)d_in[5];
    const float* bv = (const float*)d_in[6];
    const float* Wo = (const float*)d_in[7];
    const float* bo = (const float*)d_in[8];

    float* out  = (float*)d_out;
    float* attn = out + (size_t)NB * SQ * DM;

    const size_t tok = (size_t)NB * SQ * DM;   // 4,194,304
    const size_t wsz = (size_t)DM * DM;        // 1,048,576

    _Float16* xh   = (_Float16*)d_ws;
    _Float16* Wqh  = xh   + tok;
    _Float16* Wkh  = Wqh  + wsz;
    _Float16* Wvh  = Wkh  + wsz;
    _Float16* Woh  = Wvh  + wsz;
    _Float16* Qh   = Woh  + wsz;
    _Float16* Kh   = Qh   + tok;
    _Float16* Vh   = Kh   + tok;
    _Float16* ctxh = Vh   + tok;               // total ~50 MB fp16

    // 1) fp32 -> fp16 converts
    cvt1<<<dim3((int)(tok / 8 / 256)), dim3(256), 0, stream>>>(x, xh, (int)(tok / 8));
    cvt4<<<dim3((int)(wsz / 8 / 256), 4), dim3(256), 0, stream>>>(
        Wq, Wk, Wv, Wo, Wqh, Wkh, Wvh, Woh, (int)(wsz / 8));

    // 2) QKV projections (fp16 MFMA, fused via grid.z, fp16 out in [B,S,D])
    gemm_h<1><<<dim3(DM / 128, (NB * SQ) / 128, 3), dim3(256), 0, stream>>>(
        xh, Wqh, Wkh, Wvh, bq, bk, bv, Qh, Kh, Vh);

    // 3) banded attention + full attn-row write + fp16 ctx
    attn_win<<<dim3(SQ / 16, NH, NB), dim3(320), 0, stream>>>(Qh, Kh, Vh, attn, ctxh);

    // 4) output projection (fp16 MFMA, fp32 out)
    gemm_h<0><<<dim3(DM / 128, (NB * SQ) / 128, 1), dim3(256), 0, stream>>>(
        ctxh, Woh, Woh, Woh, bo, bo, bo, out, out, out);
}